// Round 8
// baseline (4650.021 us; speedup 1.0000x reference)
//
#include <hip/hip_runtime.h>
#include <hip/hip_bf16.h>

#define Bsz   1024
#define Lseq  50
#define Din   4
#define Hd    512
#define Tlen  30
#define NWG   256

typedef __hip_bfloat16 bf16;
typedef short s16x8 __attribute__((ext_vector_type(8)));
typedef short s16x4 __attribute__((ext_vector_type(4)));
typedef float f32x4 __attribute__((ext_vector_type(4)));
typedef int   i32x2 __attribute__((ext_vector_type(2)));

__device__ __forceinline__ float bf2f(bf16 x){ return __bfloat162float(x); }
__device__ __forceinline__ bf16  f2bf(float x){ return __float2bfloat16(x); }
__device__ __forceinline__ float bfbits2f(short u){
    union { unsigned int ui; float f; } v;
    v.ui = ((unsigned int)(unsigned short)u) << 16;
    return v.f;
}
__device__ __forceinline__ short f2bfbits(float x){
    bf16 h = f2bf(x); short s; __builtin_memcpy(&s, &h, 2); return s;
}
__device__ __forceinline__ float sigm(float x){ return 1.0f/(1.0f + __expf(-x)); }
// fast tanh: 1 - 2/(e^{2x}+1); saturates correctly at +-inf
__device__ __forceinline__ float ftanh(float x){
    const float e = __expf(2.0f*x);
    return 1.0f - 2.0f/(e + 1.0f);
}

// ---- sc0/sc1 write-through stores (visible at device coherence point) ----
__device__ __forceinline__ void sc_store_short(bf16* p, bf16 v){
    short s; __builtin_memcpy(&s, &v, 2);
    int si = (int)s;
    asm volatile("global_store_short %0, %1, off sc0 sc1" :: "v"(p), "v"(si) : "memory");
}
__device__ __forceinline__ void sc_store_b64(void* p, i32x2 v){
    asm volatile("global_store_dwordx2 %0, %1, off sc0 sc1" :: "v"(p), "v"(v) : "memory");
}
__device__ __forceinline__ void sc_store_b128s(void* p, s16x8 v){
    asm volatile("global_store_dwordx4 %0, %1, off sc0 sc1" :: "v"(p), "v"(v) : "memory");
}
__device__ __forceinline__ void sc_store_b128f(void* p, f32x4 v){
    asm volatile("global_store_dwordx4 %0, %1, off sc0 sc1" :: "v"(p), "v"(v) : "memory");
}
__device__ __forceinline__ i32x2 pack4(float a, float b, float c, float d){
    i32x2 v;
    v[0] = (int)(unsigned short)f2bfbits(a) | ((int)(unsigned short)f2bfbits(b) << 16);
    v[1] = (int)(unsigned short)f2bfbits(c) | ((int)(unsigned short)f2bfbits(d) << 16);
    return v;
}

// ---------------- ws layout (bytes) ----------------
#define OFF_ABUF0   (0u)
#define OFF_ABUF1   (2u<<20)
#define OFF_ATTNAP  (8u<<20)
#define OFF_XDEC    (9u<<20)
#define OFF_FLAG    ((9u<<20) + (16u<<10))
#define OFF_COMBWR  ((9u<<20) + (32u<<10))
#define OFF_ATTNWR  ((9u<<20) + (600u<<10))
#define OFF_FLAGS   ((9u<<20) + (704u<<10))
#define OFF_WCACHE  (10u<<20)
#define OFF_ENCOUT  (18u<<20)

// wcache element offsets (bf16 elements), 8-elem aligned per array
#define WC_INPUT 0
#define WC_EWIH  204800
#define WC_EWHH  212992
#define WC_EBIH  1261568
#define WC_EBHH  1263616
#define WC_AW    1265664
#define WC_AB    1291464
#define WC_CW    1291520
#define WC_CB    1555712
#define WC_DWIH  1556224
#define WC_DWHH  2604800
#define WC_DBIH  3653376
#define WC_DBHH  3655424
#define WC_OW    3657472
#define WC_OB    3659520
#define WC_TOTAL 3659524

__device__ __constant__ int WOFF[15] = {
    WC_INPUT, WC_EWIH, WC_EWHH, WC_EBIH, WC_EBHH, WC_AW, WC_AB, WC_CW,
    WC_CB, WC_DWIH, WC_DWHH, WC_DBIH, WC_DBHH, WC_OW, WC_OB };
__device__ __constant__ int WNUM[15] = {
    204800, 8192, 1048576, 2048, 2048, 25800, 50, 264192,
    512, 1048576, 1048576, 2048, 2048, 2048, 4 };

struct Ptrs15 { const void* p[15]; };

__global__ void probe_kernel(const unsigned int* __restrict__ w, int* flag){
    __shared__ int cnt;
    if (threadIdx.x == 0) cnt = 0;
    __syncthreads();
    int c = 0;
    for (int i = threadIdx.x; i < 4096; i += 256){
        unsigned e = (w[i] >> 7) & 0xFFu;
        c += (e >= 0x80u) ? 1 : 0;
    }
    atomicAdd(&cnt, c);
    __syncthreads();
    if (threadIdx.x == 0) *flag = (cnt > 400) ? 1 : 0;
}

__global__ __launch_bounds__(256) void convert_kernel(
    Ptrs15 srcs, const int* __restrict__ flag, bf16* __restrict__ dst)
{
    const int f = *flag;
    for (int idx = blockIdx.x*256 + threadIdx.x; idx < WC_TOTAL;
         idx += gridDim.x*256){
        int a = 0;
#pragma unroll
        for (int j = 1; j < 15; ++j) if (idx >= WOFF[j]) a = j;
        const int local = idx - WOFF[a];
        if (local >= WNUM[a]) continue;
        bf16 v;
        if (f) v = f2bf(((const float*)srcs.p[a])[local]);
        else   v = ((const bf16*)srcs.p[a])[local];
        dst[idx] = v;
    }
}

__global__ __launch_bounds__(256) void setup_kernel(
    bf16* __restrict__ Abuf0, bf16* __restrict__ Abuf1,
    bf16* __restrict__ combWr, bf16* __restrict__ attnWr,
    const bf16* __restrict__ cWc, const bf16* __restrict__ aWc)
{
    const unsigned idx = blockIdx.x*256u + threadIdx.x;
    if (idx < (unsigned)Bsz*Hd){
        const unsigned row = idx >> 9, col = idx & (Hd-1);
        const bf16 z = f2bf(0.0f);
        Abuf0[(size_t)row*1024 + Hd + col] = z;
        Abuf1[(size_t)row*1024 + Hd + col] = z;
    }
    if (idx < (unsigned)Hd*Hd)
        combWr[idx] = cWc[(size_t)(idx >> 9)*(Hd+Din) + Din + (idx & (Hd-1))];
    if (idx < (unsigned)Lseq*Hd)
        attnWr[idx] = aWc[(size_t)(idx >> 9)*(Hd+Din) + Din + (idx & (Hd-1))];
}

struct MegaP {
    const bf16 *input, *eWih, *eWhh, *ebih, *ebhh;
    const bf16 *aW, *ab, *cW, *cb, *dWih, *dWhh, *dbih, *dbhh, *oW, *ob;
    const bf16 *combWr, *attnWr;
    bf16 *A0, *A1, *encout, *attnap, *xdec;
    int *wflag, *gflag;
    const int *flag;
    void *dout;
};

// ---------------------------------------------------------------------------
// Persistent megakernel, mapping-agnostic sync.
// 256 WGs x 512 thr, 1 WG/CU (158.7 KB LDS).
// All cross-WG stores are sc0/sc1 write-through (visible at L3); every
// barrier ends with buffer_inv sc0 sc1 (invalidate-only; no line is ever
// dirty, so nothing is lost). Barriers are flag-based (one relaxed
// system-scope store + parallel polls) -- no serialized atomic RMW chain,
// no threadfence/wbl2.
//   PSYNC: m-group (16 WGs sharing mt = wg>>4) -- covers every local dep.
//   GSYNC: 2-level flags (32-WG leaders -> 8 gflags) -- for the h_r gather.
// enc W_hh / dec W_ih register-resident; dec W_hh slice in LDS (stride 536
// shorts = 12 dw mod 32 -> 2-way = conflict-free); c-state in registers.
// ---------------------------------------------------------------------------
__global__ __launch_bounds__(512, 2) void mega_kernel(MegaP P)
{
    __shared__ short whh_lds[128*536];   // 137,216 B
    __shared__ short hr_s[4][Hd];        // 4 KB (bf16)
    __shared__ float ctx_s[2][4][Hd];    // 16 KB
    __shared__ float aw_s[4][64];        // 1 KB

    const int wg = blockIdx.x, tid = threadIdx.x;
    const int wave = tid >> 6, lane = tid & 63;
    const int quad = lane >> 4, l15 = lane & 15;
    const int lbase = lane & ~3;
    const int f32out = *P.flag;

    int ep = 0;

    const int mt = wg >> 4, nt = wg & 15;
    const int bm0 = mt << 6, hc0 = nt << 5;
    const int wm = wave >> 2, wn = wave & 3;
    const int arow0 = bm0 + wm*32 + l15;

    auto PSYNC = [&](){
        ++ep;
        __syncthreads();
        if (tid == 0)
            __hip_atomic_store(P.wflag + wg*16, ep, __ATOMIC_RELAXED, __HIP_MEMORY_SCOPE_SYSTEM);
        if (tid < 16){
            const int* f = P.wflag + (mt*16 + tid)*16;
            while (__hip_atomic_load(f, __ATOMIC_RELAXED, __HIP_MEMORY_SCOPE_SYSTEM) < ep)
                __builtin_amdgcn_s_sleep(1);
        }
        __syncthreads();
        asm volatile("buffer_inv sc0 sc1" ::: "memory");
    };

    auto GSYNC = [&](){
        ++ep;
        __syncthreads();
        if (tid == 0)
            __hip_atomic_store(P.wflag + wg*16, ep, __ATOMIC_RELAXED, __HIP_MEMORY_SCOPE_SYSTEM);
        if ((wg & 31) == 0){
            if (tid < 32){
                const int* f = P.wflag + (wg + tid)*16;
                while (__hip_atomic_load(f, __ATOMIC_RELAXED, __HIP_MEMORY_SCOPE_SYSTEM) < ep)
                    __builtin_amdgcn_s_sleep(1);
            }
            if (tid == 0)
                __hip_atomic_store(P.gflag + (wg >> 5)*16, ep, __ATOMIC_RELAXED, __HIP_MEMORY_SCOPE_SYSTEM);
        }
        if (tid < 8){
            const int* f = P.gflag + tid*16;
            while (__hip_atomic_load(f, __ATOMIC_RELAXED, __HIP_MEMORY_SCOPE_SYSTEM) < ep)
                __builtin_amdgcn_s_sleep(1);
        }
        __syncthreads();
        asm volatile("buffer_inv sc0 sc1" ::: "memory");
    };

    bf16* bufs[2] = { P.A0, P.A1 };

    int ng[2];
#pragma unroll
    for (int nf = 0; nf < 2; ++nf){
        const int n = wn*32 + nf*16 + l15;
        ng[nf] = (n & 3)*Hd + hc0 + (n >> 2);
    }

    // ================= ENCODER =================
    float bias_e[2], wxv_e[2][4];
#pragma unroll
    for (int nf = 0; nf < 2; ++nf){
        bias_e[nf] = bf2f(P.ebih[ng[nf]]) + bf2f(P.ebhh[ng[nf]]);
        const s16x4 t4 = *reinterpret_cast<const s16x4*>(P.eWih + (size_t)ng[nf]*Din);
#pragma unroll
        for (int d = 0; d < 4; ++d) wxv_e[nf][d] = bfbits2f(t4[d]);
    }

    s16x8 breg[2][16];
#pragma unroll
    for (int nf = 0; nf < 2; ++nf)
#pragma unroll
        for (int sl = 0; sl < 16; ++sl)
            breg[nf][sl] = *reinterpret_cast<const s16x8*>(
                P.eWhh + (size_t)ng[nf]*Hd + sl*32 + quad*8);

    float creg[2][2][4];
#pragma unroll
    for (int a = 0; a < 2; ++a)
#pragma unroll
        for (int b = 0; b < 2; ++b)
#pragma unroll
            for (int r = 0; r < 4; ++r) creg[a][b][r] = 0.0f;

    for (int t = 0; t < Lseq; ++t){
        const bf16* Ain = bufs[t&1] + Hd;
        bf16* hout = bufs[(t+1)&1] + Hd;

        f32x4 acc[2][2];
#pragma unroll
        for (int mf=0; mf<2; ++mf)
#pragma unroll
            for (int nf=0; nf<2; ++nf) acc[mf][nf] = (f32x4)0.0f;

        s16x8 afr[2];
#pragma unroll
        for (int sl = 0; sl < 16; ++sl){
#pragma unroll
            for (int mf = 0; mf < 2; ++mf)
                afr[mf] = *reinterpret_cast<const s16x8*>(
                    Ain + (size_t)(arow0 + mf*16)*1024 + sl*32 + quad*8);
#pragma unroll
            for (int mf = 0; mf < 2; ++mf)
#pragma unroll
                for (int nf = 0; nf < 2; ++nf)
                    acc[mf][nf] = __builtin_amdgcn_mfma_f32_16x16x32_bf16(
                        afr[mf], breg[nf][sl], acc[mf][nf], 0, 0, 0);
        }

#pragma unroll
        for (int mf = 0; mf < 2; ++mf){
#pragma unroll
            for (int r = 0; r < 4; ++r){
                const int m = bm0 + wm*32 + mf*16 + quad*4 + r;
                const s16x4 xt = *reinterpret_cast<const s16x4*>(
                    P.input + ((size_t)m*Lseq + t)*Din);
                float xv[4];
#pragma unroll
                for (int d = 0; d < 4; ++d) xv[d] = bfbits2f(xt[d]);
#pragma unroll
                for (int nf = 0; nf < 2; ++nf){
                    const int n_loc = wn*32 + nf*16 + l15;
                    float gv = acc[mf][nf][r] + bias_e[nf]
                             + xv[0]*wxv_e[nf][0] + xv[1]*wxv_e[nf][1]
                             + xv[2]*wxv_e[nf][2] + xv[3]*wxv_e[nf][3];
                    const float gi = __shfl(gv, lbase+0);
                    const float gf = __shfl(gv, lbase+1);
                    const float gg = __shfl(gv, lbase+2);
                    const float go = __shfl(gv, lbase+3);
                    if ((lane & 3) == 0){
                        const int hcol = hc0 + (n_loc >> 2);
                        const float cn = sigm(gf)*creg[mf][nf][r] + sigm(gi)*ftanh(gg);
                        creg[mf][nf][r] = cn;
                        const float hv = sigm(go)*ftanh(cn);
                        const bf16 hb = f2bf(hv);
                        sc_store_short(hout + (size_t)m*1024 + hcol, hb);
                        sc_store_short(P.encout + ((size_t)m*Lseq + t)*Hd + hcol, hb);
                    }
                }
            }
        }
        if (t == Lseq-1) GSYNC(); else PSYNC();
    }

    // ================= DECODER =================
#pragma unroll
    for (int nf = 0; nf < 2; ++nf)
#pragma unroll
        for (int sl = 0; sl < 16; ++sl)
            breg[nf][sl] = *reinterpret_cast<const s16x8*>(
                P.dWih + (size_t)ng[nf]*Hd + sl*32 + quad*8);

    float bias_d[2];
#pragma unroll
    for (int nf = 0; nf < 2; ++nf)
        bias_d[nf] = bf2f(P.dbih[ng[nf]]) + bf2f(P.dbhh[ng[nf]]);

    // dec W_hh slice -> LDS (persists across all 30 steps); stride 536
    for (int i = tid; i < 128*64; i += 512){
        const int col = i >> 6;
        const int k8  = (i & 63) * 8;
        const int g   = (col & 3)*Hd + hc0 + (col >> 2);
        const s16x8 v = *reinterpret_cast<const s16x8*>(P.dWhh + (size_t)g*Hd + k8);
        *reinterpret_cast<s16x8*>(&whh_lds[col*536 + k8]) = v;
    }

    const int b0 = wg*4;
    const int s_uni = b0 >> 9;
    const int p0 = b0 & (Hd-1);

    // comb tile: rows bm0..+64 x cols hc0..+32
    const int cwm = wave >> 1, cwn = wave & 1;
    const int ccol = hc0 + cwn*16 + l15;
    float bias_c, wxv_c[4];
    {
        bias_c = bf2f(P.cb[ccol]);
        const s16x4 t4 = *reinterpret_cast<const s16x4*>(P.cW + (size_t)ccol*(Hd+Din));
#pragma unroll
        for (int d = 0; d < 4; ++d) wxv_c[d] = bfbits2f(t4[d]);
    }
    __syncthreads();  // whh_lds fill complete

    for (int t = 0; t < Tlen; ++t){
        const int p = t & 1;
        const bf16* hprev = bufs[p] + Hd;    // h_{t-1}, ld 1024

        // ---- D1: hr staging + pred(t-1) + attention + context ----
        {
            const s16x4 hv = *reinterpret_cast<const s16x4*>(
                hprev + (size_t)(2*tid + s_uni)*1024 + p0);
            hr_s[0][tid] = hv[0]; hr_s[1][tid] = hv[1];
            hr_s[2][tid] = hv[2]; hr_s[3][tid] = hv[3];
        }
        __syncthreads();

        if (wave < 4){
            const int b = b0 + wave;
            float x0, x1, x2, x3;
            if (t == 0){
                const bf16* xp = P.input + ((size_t)b*Lseq + (Lseq-1))*Din;
                x0 = bf2f(xp[0]); x1 = bf2f(xp[1]); x2 = bf2f(xp[2]); x3 = bf2f(xp[3]);
            } else {
                float q0=0.f, q1=0.f, q2=0.f, q3=0.f;
                const bf16* hb = hprev + (size_t)b*1024;
                for (int k = lane; k < Hd; k += 64){
                    const float hv = bf2f(hb[k]);
                    q0 += hv*bf2f(P.oW[k]);
                    q1 += hv*bf2f(P.oW[Hd+k]);
                    q2 += hv*bf2f(P.oW[2*Hd+k]);
                    q3 += hv*bf2f(P.oW[3*Hd+k]);
                }
#pragma unroll
                for (int off = 32; off; off >>= 1){
                    q0 += __shfl_down(q0, off); q1 += __shfl_down(q1, off);
                    q2 += __shfl_down(q2, off); q3 += __shfl_down(q3, off);
                }
                x0 = __shfl(q0,0) + bf2f(P.ob[0]);
                x1 = __shfl(q1,0) + bf2f(P.ob[1]);
                x2 = __shfl(q2,0) + bf2f(P.ob[2]);
                x3 = __shfl(q3,0) + bf2f(P.ob[3]);
                if (lane == 0){
                    const size_t o = ((size_t)b*Tlen + (t-1))*Din;
                    if (f32out){
                        f32x4 v; v[0]=x0; v[1]=x1; v[2]=x2; v[3]=x3;
                        sc_store_b128f((float*)P.dout + o, v);
                    } else {
                        sc_store_b64((bf16*)P.dout + o, pack4(x0,x1,x2,x3));
                    }
                }
            }
            if (lane == 0)
                sc_store_b64(P.xdec + (size_t)b*Din, pack4(x0,x1,x2,x3));

            float logit = -3.0e38f;
            if (lane < Lseq){
                float a0 = bf2f(P.ab[lane]);
                {
                    const bf16* wx = P.aW + (size_t)lane*(Hd+Din);
                    a0 += x0*bf2f(wx[0]) + x1*bf2f(wx[1]) + x2*bf2f(wx[2]) + x3*bf2f(wx[3]);
                }
                float a1 = 0.f, a2 = 0.f, a3 = 0.f;
                const bf16* wr = P.attnWr + (size_t)lane*Hd;
                for (int j = 0; j < Hd; j += 16){
                    float t4[4] = {0.f,0.f,0.f,0.f};
#pragma unroll
                    for (int q = 0; q < 4; ++q){
                        const s16x4 hw = *reinterpret_cast<const s16x4*>(&hr_s[wave][j + q*4]);
                        const s16x4 wv = *reinterpret_cast<const s16x4*>(wr + j + q*4);
                        t4[q] = bfbits2f(hw[0])*bfbits2f(wv[0]) + bfbits2f(hw[1])*bfbits2f(wv[1])
                              + bfbits2f(hw[2])*bfbits2f(wv[2]) + bfbits2f(hw[3])*bfbits2f(wv[3]);
                    }
                    a0 += t4[0]; a1 += t4[1]; a2 += t4[2]; a3 += t4[3];
                }
                logit = (a0 + a1) + (a2 + a3);
            }
            float mx = logit;
#pragma unroll
            for (int off = 32; off; off >>= 1) mx = fmaxf(mx, __shfl_xor(mx, off));
            const float e = (lane < Lseq) ? __expf(logit - mx) : 0.0f;
            float se = e;
#pragma unroll
            for (int off = 32; off; off >>= 1) se += __shfl_xor(se, off);
            aw_s[wave][lane] = e / se;
        }
        __syncthreads();

        {
            const int r = wave & 3, half = wave >> 2;
            const int b = b0 + r;
            float acc8[8] = {0.f,0.f,0.f,0.f,0.f,0.f,0.f,0.f};
            const bf16* eb = P.encout + (size_t)b*Lseq*Hd + lane*8;
            for (int i = 0; i < 25; ++i){
                const int l = half*25 + i;
                const float w = aw_s[r][l];
                const s16x8 ch = *reinterpret_cast<const s16x8*>(eb + (size_t)l*Hd);
#pragma unroll
                for (int q = 0; q < 8; ++q) acc8[q] += w * bfbits2f(ch[q]);
            }
            float* cp = &ctx_s[half][r][lane*8];
            *reinterpret_cast<float4*>(cp)     = make_float4(acc8[0],acc8[1],acc8[2],acc8[3]);
            *reinterpret_cast<float4*>(cp + 4) = make_float4(acc8[4],acc8[5],acc8[6],acc8[7]);
        }
        __syncthreads();

        if (wave < 4){
            const int b = b0 + wave;
            s16x8 ov;
#pragma unroll
            for (int q = 0; q < 8; ++q)
                ov[q] = f2bfbits(ctx_s[0][wave][lane*8+q] + ctx_s[1][wave][lane*8+q]);
            sc_store_b128s(P.attnap + (size_t)b*Hd + lane*8, ov);
        }
        PSYNC();

        // ---- D2: comb GEMM -> bufs[p] cols 0..511 ----
        {
            f32x4 cacc = (f32x4)0.0f;
            const bf16* Ab = P.attnap + (size_t)(bm0 + cwm*16 + l15)*Hd + quad*8;
#pragma unroll
            for (int kk = 0; kk < 16; ++kk){
                const s16x8 bfr = *reinterpret_cast<const s16x8*>(
                    P.combWr + (size_t)ccol*Hd + kk*32 + quad*8);
                const s16x8 afr2 = *reinterpret_cast<const s16x8*>(Ab + kk*32);
                cacc = __builtin_amdgcn_mfma_f32_16x16x32_bf16(afr2, bfr, cacc, 0, 0, 0);
            }
            bf16* outp = bufs[p];
#pragma unroll
            for (int r = 0; r < 4; ++r){
                const int m = bm0 + cwm*16 + quad*4 + r;
                const s16x4 xt = *reinterpret_cast<const s16x4*>(P.xdec + (size_t)m*Din);
                float v = cacc[r] + bias_c
                        + bfbits2f(xt[0])*wxv_c[0] + bfbits2f(xt[1])*wxv_c[1]
                        + bfbits2f(xt[2])*wxv_c[2] + bfbits2f(xt[3])*wxv_c[3];
                v = fmaxf(v, 0.0f);
                sc_store_short(outp + (size_t)m*1024 + ccol, f2bf(v));
            }
        }
        PSYNC();

        // ---- D3: dec gates ----
        {
            const bf16* Ain = bufs[p];
            bf16* hout = bufs[p^1] + Hd;
            f32x4 acc[2][2];
#pragma unroll
            for (int mf=0; mf<2; ++mf)
#pragma unroll
                for (int nf=0; nf<2; ++nf) acc[mf][nf] = (f32x4)0.0f;

            s16x8 afr[2], bfr[2];
            // K half 1: comb cols (W_ih in regs)
#pragma unroll
            for (int sl = 0; sl < 16; ++sl){
#pragma unroll
                for (int mf = 0; mf < 2; ++mf)
                    afr[mf] = *reinterpret_cast<const s16x8*>(
                        Ain + (size_t)(arow0 + mf*16)*1024 + sl*32 + quad*8);
#pragma unroll
                for (int mf = 0; mf < 2; ++mf)
#pragma unroll
                    for (int nf = 0; nf < 2; ++nf)
                        acc[mf][nf] = __builtin_amdgcn_mfma_f32_16x16x32_bf16(
                            afr[mf], breg[nf][sl], acc[mf][nf], 0, 0, 0);
            }
            // K half 2: h cols (W_hh from LDS, stride 536)
#pragma unroll
            for (int sl = 0; sl < 16; ++sl){
#pragma unroll
                for (int nf = 0; nf < 2; ++nf){
                    const int nl = wn*32 + nf*16 + l15;
                    bfr[nf] = *reinterpret_cast<const s16x8*>(
                        &whh_lds[nl*536 + sl*32 + quad*8]);
                }
#pragma unroll
                for (int mf = 0; mf < 2; ++mf)
                    afr[mf] = *reinterpret_cast<const s16x8*>(
                        Ain + (size_t)(arow0 + mf*16)*1024 + Hd + sl*32 + quad*8);
#pragma unroll
                for (int mf = 0; mf < 2; ++mf)
#pragma unroll
                    for (int nf = 0; nf < 2; ++nf)
                        acc[mf][nf] = __builtin_amdgcn_mfma_f32_16x16x32_bf16(
                            afr[mf], bfr[nf], acc[mf][nf], 0, 0, 0);
            }

#pragma unroll
            for (int mf = 0; mf < 2; ++mf){
#pragma unroll
                for (int r = 0; r < 4; ++r){
                    const int m = bm0 + wm*32 + mf*16 + quad*4 + r;
#pragma unroll
                    for (int nf = 0; nf < 2; ++nf){
                        const int n_loc = wn*32 + nf*16 + l15;
                        float gv = acc[mf][nf][r] + bias_d[nf];
                        const float gi = __shfl(gv, lbase+0);
                        const float gf = __shfl(gv, lbase+1);
                        const float gg = __shfl(gv, lbase+2);
                        const float go = __shfl(gv, lbase+3);
                        if ((lane & 3) == 0){
                            const int hcol = hc0 + (n_loc >> 2);
                            const float cn = sigm(gf)*creg[mf][nf][r] + sigm(gi)*ftanh(gg);
                            creg[mf][nf][r] = cn;
                            const float hv = sigm(go)*ftanh(cn);
                            sc_store_short(hout + (size_t)m*1024 + hcol, f2bf(hv));
                        }
                    }
                }
            }
        }
        GSYNC();
    }

    // ---- final pred (t = T-1) ----
    if (wave < 4){
        const int b = b0 + wave;
        const bf16* hb = bufs[Tlen & 1] + Hd + (size_t)b*1024;
        float q0=0.f, q1=0.f, q2=0.f, q3=0.f;
        for (int k = lane; k < Hd; k += 64){
            const float hv = bf2f(hb[k]);
            q0 += hv*bf2f(P.oW[k]);
            q1 += hv*bf2f(P.oW[Hd+k]);
            q2 += hv*bf2f(P.oW[2*Hd+k]);
            q3 += hv*bf2f(P.oW[3*Hd+k]);
        }
#pragma unroll
        for (int off = 32; off; off >>= 1){
            q0 += __shfl_down(q0, off); q1 += __shfl_down(q1, off);
            q2 += __shfl_down(q2, off); q3 += __shfl_down(q3, off);
        }
        if (lane == 0){
            const size_t o = ((size_t)b*Tlen + (Tlen-1))*Din;
            const float r0 = q0 + bf2f(P.ob[0]), r1 = q1 + bf2f(P.ob[1]);
            const float r2 = q2 + bf2f(P.ob[2]), r3 = q3 + bf2f(P.ob[3]);
            if (f32out){
                f32x4 v; v[0]=r0; v[1]=r1; v[2]=r2; v[3]=r3;
                sc_store_b128f((float*)P.dout + o, v);
            } else {
                sc_store_b64((bf16*)P.dout + o, pack4(r0,r1,r2,r3));
            }
        }
    }
}

extern "C" void kernel_launch(void* const* d_in, const int* in_sizes, int n_in,
                              void* d_out, int out_size, void* d_ws, size_t ws_size,
                              hipStream_t stream)
{
    char* ws = (char*)d_ws;
    bf16*  Abuf0   = (bf16*)(ws + OFF_ABUF0);
    bf16*  Abuf1   = (bf16*)(ws + OFF_ABUF1);
    bf16*  attnap  = (bf16*)(ws + OFF_ATTNAP);
    bf16*  xdec    = (bf16*)(ws + OFF_XDEC);
    int*   flag    = (int*)(ws + OFF_FLAG);
    bf16*  combWr  = (bf16*)(ws + OFF_COMBWR);
    bf16*  attnWr  = (bf16*)(ws + OFF_ATTNWR);
    int*   flags   = (int*)(ws + OFF_FLAGS);
    bf16*  wc      = (bf16*)(ws + OFF_WCACHE);
    bf16*  enc_out = (bf16*)(ws + OFF_ENCOUT);

    hipMemsetAsync(flags, 0, 20480, stream);

    probe_kernel<<<1, 256, 0, stream>>>((const unsigned int*)d_in[3], flag);

    Ptrs15 srcs;
    srcs.p[0]=d_in[0];  srcs.p[1]=d_in[2];  srcs.p[2]=d_in[3];  srcs.p[3]=d_in[4];
    srcs.p[4]=d_in[5];  srcs.p[5]=d_in[6];  srcs.p[6]=d_in[7];  srcs.p[7]=d_in[8];
    srcs.p[8]=d_in[9];  srcs.p[9]=d_in[10]; srcs.p[10]=d_in[11];srcs.p[11]=d_in[12];
    srcs.p[12]=d_in[13];srcs.p[13]=d_in[14];srcs.p[14]=d_in[15];
    convert_kernel<<<1024, 256, 0, stream>>>(srcs, flag, wc);

    setup_kernel<<<2048, 256, 0, stream>>>(Abuf0, Abuf1, combWr, attnWr,
                                           wc+WC_CW, wc+WC_AW);

    MegaP P;
    P.input = wc+WC_INPUT; P.eWih = wc+WC_EWIH; P.eWhh = wc+WC_EWHH;
    P.ebih = wc+WC_EBIH;   P.ebhh = wc+WC_EBHH;
    P.aW = wc+WC_AW;  P.ab = wc+WC_AB;  P.cW = wc+WC_CW;  P.cb = wc+WC_CB;
    P.dWih = wc+WC_DWIH; P.dWhh = wc+WC_DWHH; P.dbih = wc+WC_DBIH; P.dbhh = wc+WC_DBHH;
    P.oW = wc+WC_OW;  P.ob = wc+WC_OB;
    P.combWr = combWr; P.attnWr = attnWr;
    P.A0 = Abuf0; P.A1 = Abuf1; P.encout = enc_out; P.attnap = attnap; P.xdec = xdec;
    P.wflag = flags; P.gflag = flags + 256*16;
    P.flag = flag; P.dout = d_out;

    mega_kernel<<<NWG, 512, 0, stream>>>(P);
}

// Round 9
// 3849.783 us; speedup vs baseline: 1.2079x; 1.2079x over previous
//
#include <hip/hip_runtime.h>
#include <hip/hip_bf16.h>

#define Bsz   1024
#define Lseq  50
#define Din   4
#define Hd    512
#define Tlen  30
#define NWG   256

typedef __hip_bfloat16 bf16;
typedef short s16x8 __attribute__((ext_vector_type(8)));
typedef short s16x4 __attribute__((ext_vector_type(4)));
typedef float f32x4 __attribute__((ext_vector_type(4)));
typedef int   i32x2 __attribute__((ext_vector_type(2)));

__device__ __forceinline__ float bf2f(bf16 x){ return __bfloat162float(x); }
__device__ __forceinline__ bf16  f2bf(float x){ return __float2bfloat16(x); }
__device__ __forceinline__ float bfbits2f(short u){
    union { unsigned int ui; float f; } v;
    v.ui = ((unsigned int)(unsigned short)u) << 16;
    return v.f;
}
__device__ __forceinline__ short f2bfbits(float x){
    bf16 h = f2bf(x); short s; __builtin_memcpy(&s, &h, 2); return s;
}
__device__ __forceinline__ float sigm(float x){ return 1.0f/(1.0f + __expf(-x)); }
__device__ __forceinline__ float ftanh(float x){
    const float e = __expf(2.0f*x);
    return 1.0f - 2.0f/(e + 1.0f);
}
__device__ __forceinline__ i32x2 pack4(float a, float b, float c, float d){
    i32x2 v;
    v[0] = (int)(unsigned short)f2bfbits(a) | ((int)(unsigned short)f2bfbits(b) << 16);
    v[1] = (int)(unsigned short)f2bfbits(c) | ((int)(unsigned short)f2bfbits(d) << 16);
    return v;
}

// ---------------- ws layout (bytes) ----------------
#define OFF_ABUF0   (0u)
#define OFF_ABUF1   (2u<<20)
#define OFF_ATTNAP  (8u<<20)
#define OFF_XDEC    (9u<<20)
#define OFF_FLAG    ((9u<<20) + (16u<<10))
#define OFF_COMBWR  ((9u<<20) + (32u<<10))
#define OFF_ATTNWR  ((9u<<20) + (600u<<10))
#define OFF_FLAGS   ((9u<<20) + (704u<<10))
#define OFF_WCACHE  (10u<<20)
#define OFF_ENCOUT  (18u<<20)

// wcache element offsets (bf16 elements), 8-elem aligned per array
#define WC_INPUT 0
#define WC_EWIH  204800
#define WC_EWHH  212992
#define WC_EBIH  1261568
#define WC_EBHH  1263616
#define WC_AW    1265664
#define WC_AB    1291464
#define WC_CW    1291520
#define WC_CB    1555712
#define WC_DWIH  1556224
#define WC_DWHH  2604800
#define WC_DBIH  3653376
#define WC_DBHH  3655424
#define WC_OW    3657472
#define WC_OB    3659520
#define WC_TOTAL 3659524

__device__ __constant__ int WOFF[15] = {
    WC_INPUT, WC_EWIH, WC_EWHH, WC_EBIH, WC_EBHH, WC_AW, WC_AB, WC_CW,
    WC_CB, WC_DWIH, WC_DWHH, WC_DBIH, WC_DBHH, WC_OW, WC_OB };
__device__ __constant__ int WNUM[15] = {
    204800, 8192, 1048576, 2048, 2048, 25800, 50, 264192,
    512, 1048576, 1048576, 2048, 2048, 2048, 4 };

struct Ptrs15 { const void* p[15]; };

__global__ void probe_kernel(const unsigned int* __restrict__ w, int* flag){
    __shared__ int cnt;
    if (threadIdx.x == 0) cnt = 0;
    __syncthreads();
    int c = 0;
    for (int i = threadIdx.x; i < 4096; i += 256){
        unsigned e = (w[i] >> 7) & 0xFFu;
        c += (e >= 0x80u) ? 1 : 0;
    }
    atomicAdd(&cnt, c);
    __syncthreads();
    if (threadIdx.x == 0) *flag = (cnt > 400) ? 1 : 0;
}

__global__ __launch_bounds__(256) void convert_kernel(
    Ptrs15 srcs, const int* __restrict__ flag, bf16* __restrict__ dst)
{
    const int f = *flag;
    for (int idx = blockIdx.x*256 + threadIdx.x; idx < WC_TOTAL;
         idx += gridDim.x*256){
        int a = 0;
#pragma unroll
        for (int j = 1; j < 15; ++j) if (idx >= WOFF[j]) a = j;
        const int local = idx - WOFF[a];
        if (local >= WNUM[a]) continue;
        bf16 v;
        if (f) v = f2bf(((const float*)srcs.p[a])[local]);
        else   v = ((const bf16*)srcs.p[a])[local];
        dst[idx] = v;
    }
}

__global__ __launch_bounds__(256) void setup_kernel(
    bf16* __restrict__ Abuf0, bf16* __restrict__ Abuf1,
    bf16* __restrict__ combWr, bf16* __restrict__ attnWr,
    const bf16* __restrict__ cWc, const bf16* __restrict__ aWc)
{
    const unsigned idx = blockIdx.x*256u + threadIdx.x;
    if (idx < (unsigned)Bsz*Hd){
        const unsigned row = idx >> 9, col = idx & (Hd-1);
        const bf16 z = f2bf(0.0f);
        Abuf0[(size_t)row*1024 + Hd + col] = z;
        Abuf1[(size_t)row*1024 + Hd + col] = z;
    }
    if (idx < (unsigned)Hd*Hd)
        combWr[idx] = cWc[(size_t)(idx >> 9)*(Hd+Din) + Din + (idx & (Hd-1))];
    if (idx < (unsigned)Lseq*Hd)
        attnWr[idx] = aWc[(size_t)(idx >> 9)*(Hd+Din) + Din + (idx & (Hd-1))];
}

struct MegaP {
    const bf16 *input, *eWih, *eWhh, *ebih, *ebhh;
    const bf16 *aW, *ab, *cW, *cb, *dWih, *dWhh, *dbih, *dbhh, *oW, *ob;
    const bf16 *combWr, *attnWr;
    bf16 *A0, *A1, *encout, *attnap, *xdec;
    int *wflag, *gflag, *xccmap;
    const int *flag;
    void *dout;
};

// ---------------------------------------------------------------------------
// Persistent megakernel. 256 WGs x 512 thr, 1 WG/CU.
// grp = wg&7 (XCD under round-robin dispatch; VERIFIED via HW_REG_XCC_ID
// consistency check, else fall back to fully-fenced barriers).
// Tiling is XCD-local: grp owns batch rows grp*128..+128 and all state for
// them, so every per-step dependency except the h_r reshape gather stays in
// the XCD's L2.
//   XSYNC: flag barrier over the 32 grp members + L1-only buffer_inv.
//          Plain write-back stores remain valid in the shared L2.
//   GSYNC: threadfence (L2 writeback) -> flags -> buffer_inv sc0 sc1 ->
//          second flag round (no WG may write until all have invalidated).
// enc W_hh / dec W_ih in registers; dec W_hh slice in LDS; c-state in regs.
// ctx_s transposed [2][4][8][64] -> conflict-free LDS.
// ---------------------------------------------------------------------------
__global__ __launch_bounds__(512, 2) void mega_kernel(MegaP P)
{
    __shared__ short whh_lds[128*536];     // 137,216 B
    __shared__ short hr_s[4][Hd];          // 4 KB
    __shared__ float ctx_s[2][4][8][64];   // 16 KB
    __shared__ float aw_s[4][64];          // 1 KB
    __shared__ int   xmap_s[NWG];          // 1 KB
    __shared__ int   info_s[2];

    const int wg = blockIdx.x, tid = threadIdx.x;
    const int wave = tid >> 6, lane = tid & 63;
    const int quad = lane >> 4, l15 = lane & 15;
    const int lbase = lane & ~3;
    const int f32out = *P.flag;

    const int grp = wg & 7, rank = wg >> 3;

    int ep = 0;

    auto flag_round = [&](bool fence){
        ++ep;
        __syncthreads();
        if (tid == 0){
            if (fence) __threadfence();
            __hip_atomic_store(P.wflag + wg*16, ep, __ATOMIC_RELAXED, __HIP_MEMORY_SCOPE_SYSTEM);
        }
        if (rank == 0){
            if (tid < 32){
                int* f = P.wflag + (tid*8 + grp)*16;
                while (__hip_atomic_load(f, __ATOMIC_RELAXED, __HIP_MEMORY_SCOPE_SYSTEM) < ep)
                    __builtin_amdgcn_s_sleep(1);
            }
            __syncthreads();
            if (tid == 0)
                __hip_atomic_store(P.gflag + grp*16, ep, __ATOMIC_RELAXED, __HIP_MEMORY_SCOPE_SYSTEM);
        }
        if (tid < 8){
            int* f = P.gflag + tid*16;
            while (__hip_atomic_load(f, __ATOMIC_RELAXED, __HIP_MEMORY_SCOPE_SYSTEM) < ep)
                __builtin_amdgcn_s_sleep(1);
        }
        __syncthreads();
    };

    auto GSYNC = [&](){
        flag_round(true);                               // all writes in L3
        asm volatile("buffer_inv sc0 sc1" ::: "memory"); // clean lines only
        __syncthreads();
        flag_round(false);                              // gate re-writers
    };

    auto XSYNC = [&](int balv){
        if (!balv){ GSYNC(); return; }
        ++ep;
        __syncthreads();
        if (tid == 0)
            __hip_atomic_store(P.wflag + wg*16, ep, __ATOMIC_RELAXED, __HIP_MEMORY_SCOPE_SYSTEM);
        if (tid < 32){
            int* f = P.wflag + (tid*8 + grp)*16;
            while (__hip_atomic_load(f, __ATOMIC_RELAXED, __HIP_MEMORY_SCOPE_SYSTEM) < ep)
                __builtin_amdgcn_s_sleep(1);
        }
        __syncthreads();
        asm volatile("buffer_inv" ::: "memory");        // L1 only; L2 warm
    };

    // ---- XCD mapping verification ----
    if (tid == 0){
        int xcc = 0;
        asm volatile("s_getreg_b32 %0, hwreg(HW_REG_XCC_ID)" : "=s"(xcc));
        P.xccmap[wg] = xcc & 7;
    }
    GSYNC();
    if (tid < NWG) xmap_s[tid] = P.xccmap[tid];
    __syncthreads();
    if (tid == 0){
        int ok = 1;
        for (int g = 0; g < 8; ++g){
            const int x0 = xmap_s[g];
            for (int i = 1; i < 32; ++i) ok &= (xmap_s[i*8 + g] == x0);
        }
        info_s[0] = ok;
    }
    __syncthreads();
    const int bal = info_s[0];

    bf16* bufs[2] = { P.A0, P.A1 };

    // ---- XCD-local tiling ----
    const int mt = grp*2 + (rank >> 4), nt = rank & 15;
    const int bm0 = mt << 6, hc0 = nt << 5;
    const int wm = wave >> 2, wn = wave & 3;
    const int arow0 = bm0 + wm*32 + l15;

    int ng[2];
#pragma unroll
    for (int nf = 0; nf < 2; ++nf){
        const int n = wn*32 + nf*16 + l15;
        ng[nf] = (n & 3)*Hd + hc0 + (n >> 2);
    }

    // ================= ENCODER =================
    float bias_e[2], wxv_e[2][4];
#pragma unroll
    for (int nf = 0; nf < 2; ++nf){
        bias_e[nf] = bf2f(P.ebih[ng[nf]]) + bf2f(P.ebhh[ng[nf]]);
        const s16x4 t4 = *reinterpret_cast<const s16x4*>(P.eWih + (size_t)ng[nf]*Din);
#pragma unroll
        for (int d = 0; d < 4; ++d) wxv_e[nf][d] = bfbits2f(t4[d]);
    }

    s16x8 breg[2][16];
#pragma unroll
    for (int nf = 0; nf < 2; ++nf)
#pragma unroll
        for (int sl = 0; sl < 16; ++sl)
            breg[nf][sl] = *reinterpret_cast<const s16x8*>(
                P.eWhh + (size_t)ng[nf]*Hd + sl*32 + quad*8);

    float creg[2][2][4];
#pragma unroll
    for (int a = 0; a < 2; ++a)
#pragma unroll
        for (int b = 0; b < 2; ++b)
#pragma unroll
            for (int r = 0; r < 4; ++r) creg[a][b][r] = 0.0f;

    for (int t = 0; t < Lseq; ++t){
        const bf16* Ain = bufs[t&1] + Hd;
        bf16* hout = bufs[(t+1)&1] + Hd;

        f32x4 acc[2][2];
#pragma unroll
        for (int mf=0; mf<2; ++mf)
#pragma unroll
            for (int nf=0; nf<2; ++nf) acc[mf][nf] = (f32x4)0.0f;

        s16x8 afr[2];
#pragma unroll
        for (int sl = 0; sl < 16; ++sl){
#pragma unroll
            for (int mf = 0; mf < 2; ++mf)
                afr[mf] = *reinterpret_cast<const s16x8*>(
                    Ain + (size_t)(arow0 + mf*16)*1024 + sl*32 + quad*8);
#pragma unroll
            for (int mf = 0; mf < 2; ++mf)
#pragma unroll
                for (int nf = 0; nf < 2; ++nf)
                    acc[mf][nf] = __builtin_amdgcn_mfma_f32_16x16x32_bf16(
                        afr[mf], breg[nf][sl], acc[mf][nf], 0, 0, 0);
        }

#pragma unroll
        for (int mf = 0; mf < 2; ++mf){
#pragma unroll
            for (int r = 0; r < 4; ++r){
                const int m = bm0 + wm*32 + mf*16 + quad*4 + r;
                const s16x4 xt = *reinterpret_cast<const s16x4*>(
                    P.input + ((size_t)m*Lseq + t)*Din);
                float xv[4];
#pragma unroll
                for (int d = 0; d < 4; ++d) xv[d] = bfbits2f(xt[d]);
#pragma unroll
                for (int nf = 0; nf < 2; ++nf){
                    const int n_loc = wn*32 + nf*16 + l15;
                    float gv = acc[mf][nf][r] + bias_e[nf]
                             + xv[0]*wxv_e[nf][0] + xv[1]*wxv_e[nf][1]
                             + xv[2]*wxv_e[nf][2] + xv[3]*wxv_e[nf][3];
                    const float gi = __shfl(gv, lbase+0);
                    const float gf = __shfl(gv, lbase+1);
                    const float gg = __shfl(gv, lbase+2);
                    const float go = __shfl(gv, lbase+3);
                    if ((lane & 3) == 0){
                        const int hcol = hc0 + (n_loc >> 2);
                        const float cn = sigm(gf)*creg[mf][nf][r] + sigm(gi)*ftanh(gg);
                        creg[mf][nf][r] = cn;
                        const float hv = sigm(go)*ftanh(cn);
                        const bf16 hb = f2bf(hv);
                        hout[(size_t)m*1024 + hcol] = hb;
                        P.encout[((size_t)m*Lseq + t)*Hd + hcol] = hb;
                    }
                }
            }
        }
        if (t == Lseq-1) GSYNC(); else XSYNC(bal);
    }

    // ================= DECODER =================
#pragma unroll
    for (int nf = 0; nf < 2; ++nf)
#pragma unroll
        for (int sl = 0; sl < 16; ++sl)
            breg[nf][sl] = *reinterpret_cast<const s16x8*>(
                P.dWih + (size_t)ng[nf]*Hd + sl*32 + quad*8);

    float bias_d[2];
#pragma unroll
    for (int nf = 0; nf < 2; ++nf)
        bias_d[nf] = bf2f(P.dbih[ng[nf]]) + bf2f(P.dbhh[ng[nf]]);

    // dec W_hh slice -> LDS (persists across all 30 steps)
    for (int i = tid; i < 128*64; i += 512){
        const int col = i >> 6;
        const int k8  = (i & 63) * 8;
        const int g   = (col & 3)*Hd + hc0 + (col >> 2);
        const s16x8 v = *reinterpret_cast<const s16x8*>(P.dWhh + (size_t)g*Hd + k8);
        *reinterpret_cast<s16x8*>(&whh_lds[col*536 + k8]) = v;
    }

    const int b0 = grp*128 + rank*4;
    const int s_uni = b0 >> 9;
    const int p0 = b0 & (Hd-1);

    const int cwm = wave >> 1, cwn = wave & 1;
    const int ccol = hc0 + cwn*16 + l15;
    float bias_c, wxv_c[4];
    {
        bias_c = bf2f(P.cb[ccol]);
        const s16x4 t4 = *reinterpret_cast<const s16x4*>(P.cW + (size_t)ccol*(Hd+Din));
#pragma unroll
        for (int d = 0; d < 4; ++d) wxv_c[d] = bfbits2f(t4[d]);
    }
    __syncthreads();  // whh_lds fill complete

    for (int t = 0; t < Tlen; ++t){
        const int p = t & 1;
        const bf16* hprev = bufs[p] + Hd;

        // ---- D1: hr staging + pred(t-1) + attention + context ----
        {
            const s16x4 hv = *reinterpret_cast<const s16x4*>(
                hprev + (size_t)(2*tid + s_uni)*1024 + p0);
            hr_s[0][tid] = hv[0]; hr_s[1][tid] = hv[1];
            hr_s[2][tid] = hv[2]; hr_s[3][tid] = hv[3];
        }
        __syncthreads();

        if (wave < 4){
            const int b = b0 + wave;
            float x0, x1, x2, x3;
            if (t == 0){
                const bf16* xp = P.input + ((size_t)b*Lseq + (Lseq-1))*Din;
                x0 = bf2f(xp[0]); x1 = bf2f(xp[1]); x2 = bf2f(xp[2]); x3 = bf2f(xp[3]);
            } else {
                float q0=0.f, q1=0.f, q2=0.f, q3=0.f;
                const bf16* hb = hprev + (size_t)b*1024;
                for (int k = lane; k < Hd; k += 64){
                    const float hv = bf2f(hb[k]);
                    q0 += hv*bf2f(P.oW[k]);
                    q1 += hv*bf2f(P.oW[Hd+k]);
                    q2 += hv*bf2f(P.oW[2*Hd+k]);
                    q3 += hv*bf2f(P.oW[3*Hd+k]);
                }
#pragma unroll
                for (int off = 32; off; off >>= 1){
                    q0 += __shfl_down(q0, off); q1 += __shfl_down(q1, off);
                    q2 += __shfl_down(q2, off); q3 += __shfl_down(q3, off);
                }
                x0 = __shfl(q0,0) + bf2f(P.ob[0]);
                x1 = __shfl(q1,0) + bf2f(P.ob[1]);
                x2 = __shfl(q2,0) + bf2f(P.ob[2]);
                x3 = __shfl(q3,0) + bf2f(P.ob[3]);
                if (lane == 0){
                    const size_t o = ((size_t)b*Tlen + (t-1))*Din;
                    if (f32out){
                        float* dp = (float*)P.dout + o;
                        dp[0]=x0; dp[1]=x1; dp[2]=x2; dp[3]=x3;
                    } else {
                        *reinterpret_cast<i32x2*>((bf16*)P.dout + o) = pack4(x0,x1,x2,x3);
                    }
                }
            }
            if (lane == 0)
                *reinterpret_cast<i32x2*>(P.xdec + (size_t)b*Din) = pack4(x0,x1,x2,x3);

            float logit = -3.0e38f;
            if (lane < Lseq){
                float a0 = bf2f(P.ab[lane]);
                {
                    const bf16* wx = P.aW + (size_t)lane*(Hd+Din);
                    a0 += x0*bf2f(wx[0]) + x1*bf2f(wx[1]) + x2*bf2f(wx[2]) + x3*bf2f(wx[3]);
                }
                float a1 = 0.f, a2 = 0.f, a3 = 0.f;
                const bf16* wr = P.attnWr + (size_t)lane*Hd;
                for (int j = 0; j < Hd; j += 16){
                    float t4[4] = {0.f,0.f,0.f,0.f};
#pragma unroll
                    for (int q = 0; q < 4; ++q){
                        const s16x4 hw = *reinterpret_cast<const s16x4*>(&hr_s[wave][j + q*4]);
                        const s16x4 wv = *reinterpret_cast<const s16x4*>(wr + j + q*4);
                        t4[q] = bfbits2f(hw[0])*bfbits2f(wv[0]) + bfbits2f(hw[1])*bfbits2f(wv[1])
                              + bfbits2f(hw[2])*bfbits2f(wv[2]) + bfbits2f(hw[3])*bfbits2f(wv[3]);
                    }
                    a0 += t4[0]; a1 += t4[1]; a2 += t4[2]; a3 += t4[3];
                }
                logit = (a0 + a1) + (a2 + a3);
            }
            float mx = logit;
#pragma unroll
            for (int off = 32; off; off >>= 1) mx = fmaxf(mx, __shfl_xor(mx, off));
            const float e = (lane < Lseq) ? __expf(logit - mx) : 0.0f;
            float se = e;
#pragma unroll
            for (int off = 32; off; off >>= 1) se += __shfl_xor(se, off);
            aw_s[wave][lane] = e / se;
        }
        __syncthreads();

        {
            const int r = wave & 3, half = wave >> 2;
            const int b = b0 + r;
            float acc8[8] = {0.f,0.f,0.f,0.f,0.f,0.f,0.f,0.f};
            const bf16* eb = P.encout + (size_t)b*Lseq*Hd + lane*8;
            for (int i = 0; i < 25; ++i){
                const int l = half*25 + i;
                const float w = aw_s[r][l];
                const s16x8 ch = *reinterpret_cast<const s16x8*>(eb + (size_t)l*Hd);
#pragma unroll
                for (int q = 0; q < 8; ++q) acc8[q] += w * bfbits2f(ch[q]);
            }
#pragma unroll
            for (int q = 0; q < 8; ++q) ctx_s[half][r][q][lane] = acc8[q];
        }
        __syncthreads();

        if (wave < 4){
            const int b = b0 + wave;
            s16x8 ov;
#pragma unroll
            for (int q = 0; q < 8; ++q)
                ov[q] = f2bfbits(ctx_s[0][wave][q][lane] + ctx_s[1][wave][q][lane]);
            *reinterpret_cast<s16x8*>(P.attnap + (size_t)b*Hd + lane*8) = ov;
        }
        XSYNC(bal);

        // ---- D2: comb GEMM -> bufs[p] cols 0..511 ----
        {
            f32x4 cacc = (f32x4)0.0f;
            const bf16* Ab = P.attnap + (size_t)(bm0 + cwm*16 + l15)*Hd + quad*8;
#pragma unroll
            for (int kk = 0; kk < 16; ++kk){
                const s16x8 bfr = *reinterpret_cast<const s16x8*>(
                    P.combWr + (size_t)ccol*Hd + kk*32 + quad*8);
                const s16x8 afr2 = *reinterpret_cast<const s16x8*>(Ab + kk*32);
                cacc = __builtin_amdgcn_mfma_f32_16x16x32_bf16(afr2, bfr, cacc, 0, 0, 0);
            }
            bf16* outp = bufs[p];
#pragma unroll
            for (int r = 0; r < 4; ++r){
                const int m = bm0 + cwm*16 + quad*4 + r;
                const s16x4 xt = *reinterpret_cast<const s16x4*>(P.xdec + (size_t)m*Din);
                float v = cacc[r] + bias_c
                        + bfbits2f(xt[0])*wxv_c[0] + bfbits2f(xt[1])*wxv_c[1]
                        + bfbits2f(xt[2])*wxv_c[2] + bfbits2f(xt[3])*wxv_c[3];
                v = fmaxf(v, 0.0f);
                outp[(size_t)m*1024 + ccol] = f2bf(v);
            }
        }
        XSYNC(bal);

        // ---- D3: dec gates ----
        {
            const bf16* Ain = bufs[p];
            bf16* hout = bufs[p^1] + Hd;
            f32x4 acc[2][2];
#pragma unroll
            for (int mf=0; mf<2; ++mf)
#pragma unroll
                for (int nf=0; nf<2; ++nf) acc[mf][nf] = (f32x4)0.0f;

            s16x8 afr[2], bfr[2];
#pragma unroll
            for (int sl = 0; sl < 16; ++sl){
#pragma unroll
                for (int mf = 0; mf < 2; ++mf)
                    afr[mf] = *reinterpret_cast<const s16x8*>(
                        Ain + (size_t)(arow0 + mf*16)*1024 + sl*32 + quad*8);
#pragma unroll
                for (int mf = 0; mf < 2; ++mf)
#pragma unroll
                    for (int nf = 0; nf < 2; ++nf)
                        acc[mf][nf] = __builtin_amdgcn_mfma_f32_16x16x32_bf16(
                            afr[mf], breg[nf][sl], acc[mf][nf], 0, 0, 0);
            }
#pragma unroll
            for (int sl = 0; sl < 16; ++sl){
#pragma unroll
                for (int nf = 0; nf < 2; ++nf){
                    const int nl = wn*32 + nf*16 + l15;
                    bfr[nf] = *reinterpret_cast<const s16x8*>(
                        &whh_lds[nl*536 + sl*32 + quad*8]);
                }
#pragma unroll
                for (int mf = 0; mf < 2; ++mf)
                    afr[mf] = *reinterpret_cast<const s16x8*>(
                        Ain + (size_t)(arow0 + mf*16)*1024 + Hd + sl*32 + quad*8);
#pragma unroll
                for (int mf = 0; mf < 2; ++mf)
#pragma unroll
                    for (int nf = 0; nf < 2; ++nf)
                        acc[mf][nf] = __builtin_amdgcn_mfma_f32_16x16x32_bf16(
                            afr[mf], bfr[nf], acc[mf][nf], 0, 0, 0);
            }

#pragma unroll
            for (int mf = 0; mf < 2; ++mf){
#pragma unroll
                for (int r = 0; r < 4; ++r){
                    const int m = bm0 + wm*32 + mf*16 + quad*4 + r;
#pragma unroll
                    for (int nf = 0; nf < 2; ++nf){
                        const int n_loc = wn*32 + nf*16 + l15;
                        float gv = acc[mf][nf][r] + bias_d[nf];
                        const float gi = __shfl(gv, lbase+0);
                        const float gf = __shfl(gv, lbase+1);
                        const float gg = __shfl(gv, lbase+2);
                        const float go = __shfl(gv, lbase+3);
                        if ((lane & 3) == 0){
                            const int hcol = hc0 + (n_loc >> 2);
                            const float cn = sigm(gf)*creg[mf][nf][r] + sigm(gi)*ftanh(gg);
                            creg[mf][nf][r] = cn;
                            const float hv = sigm(go)*ftanh(cn);
                            hout[(size_t)m*1024 + hcol] = f2bf(hv);
                        }
                    }
                }
            }
        }
        GSYNC();
    }

    // ---- final pred (t = T-1) ----
    if (wave < 4){
        const int b = b0 + wave;
        const bf16* hb = bufs[Tlen & 1] + Hd + (size_t)b*1024;
        float q0=0.f, q1=0.f, q2=0.f, q3=0.f;
        for (int k = lane; k < Hd; k += 64){
            const float hv = bf2f(hb[k]);
            q0 += hv*bf2f(P.oW[k]);
            q1 += hv*bf2f(P.oW[Hd+k]);
            q2 += hv*bf2f(P.oW[2*Hd+k]);
            q3 += hv*bf2f(P.oW[3*Hd+k]);
        }
#pragma unroll
        for (int off = 32; off; off >>= 1){
            q0 += __shfl_down(q0, off); q1 += __shfl_down(q1, off);
            q2 += __shfl_down(q2, off); q3 += __shfl_down(q3, off);
        }
        if (lane == 0){
            const size_t o = ((size_t)b*Tlen + (Tlen-1))*Din;
            const float r0 = q0 + bf2f(P.ob[0]), r1 = q1 + bf2f(P.ob[1]);
            const float r2 = q2 + bf2f(P.ob[2]), r3 = q3 + bf2f(P.ob[3]);
            if (f32out){
                float* dp = (float*)P.dout + o;
                dp[0]=r0; dp[1]=r1; dp[2]=r2; dp[3]=r3;
            } else {
                *reinterpret_cast<i32x2*>((bf16*)P.dout + o) = pack4(r0,r1,r2,r3);
            }
        }
    }
}

extern "C" void kernel_launch(void* const* d_in, const int* in_sizes, int n_in,
                              void* d_out, int out_size, void* d_ws, size_t ws_size,
                              hipStream_t stream)
{
    char* ws = (char*)d_ws;
    bf16*  Abuf0   = (bf16*)(ws + OFF_ABUF0);
    bf16*  Abuf1   = (bf16*)(ws + OFF_ABUF1);
    bf16*  attnap  = (bf16*)(ws + OFF_ATTNAP);
    bf16*  xdec    = (bf16*)(ws + OFF_XDEC);
    int*   flag    = (int*)(ws + OFF_FLAG);
    bf16*  combWr  = (bf16*)(ws + OFF_COMBWR);
    bf16*  attnWr  = (bf16*)(ws + OFF_ATTNWR);
    int*   flags   = (int*)(ws + OFF_FLAGS);
    bf16*  wc      = (bf16*)(ws + OFF_WCACHE);
    bf16*  enc_out = (bf16*)(ws + OFF_ENCOUT);

    hipMemsetAsync(flags, 0, 20480, stream);

    probe_kernel<<<1, 256, 0, stream>>>((const unsigned int*)d_in[3], flag);

    Ptrs15 srcs;
    srcs.p[0]=d_in[0];  srcs.p[1]=d_in[2];  srcs.p[2]=d_in[3];  srcs.p[3]=d_in[4];
    srcs.p[4]=d_in[5];  srcs.p[5]=d_in[6];  srcs.p[6]=d_in[7];  srcs.p[7]=d_in[8];
    srcs.p[8]=d_in[9];  srcs.p[9]=d_in[10]; srcs.p[10]=d_in[11];srcs.p[11]=d_in[12];
    srcs.p[12]=d_in[13];srcs.p[13]=d_in[14];srcs.p[14]=d_in[15];
    convert_kernel<<<1024, 256, 0, stream>>>(srcs, flag, wc);

    setup_kernel<<<2048, 256, 0, stream>>>(Abuf0, Abuf1, combWr, attnWr,
                                           wc+WC_CW, wc+WC_AW);

    MegaP P;
    P.input = wc+WC_INPUT; P.eWih = wc+WC_EWIH; P.eWhh = wc+WC_EWHH;
    P.ebih = wc+WC_EBIH;   P.ebhh = wc+WC_EBHH;
    P.aW = wc+WC_AW;  P.ab = wc+WC_AB;  P.cW = wc+WC_CW;  P.cb = wc+WC_CB;
    P.dWih = wc+WC_DWIH; P.dWhh = wc+WC_DWHH; P.dbih = wc+WC_DBIH; P.dbhh = wc+WC_DBHH;
    P.oW = wc+WC_OW;  P.ob = wc+WC_OB;
    P.combWr = combWr; P.attnWr = attnWr;
    P.A0 = Abuf0; P.A1 = Abuf1; P.encout = enc_out; P.attnap = attnap; P.xdec = xdec;
    P.wflag = flags; P.gflag = flags + 256*16; P.xccmap = flags + 256*16 + 8*16;
    P.flag = flag; P.dout = d_out;

    mega_kernel<<<NWG, 512, 0, stream>>>(P);
}

// Round 10
// 3503.511 us; speedup vs baseline: 1.3272x; 1.0988x over previous
//
#include <hip/hip_runtime.h>
#include <hip/hip_bf16.h>

#define Bsz   1024
#define Lseq  50
#define Din   4
#define Hd    512
#define Tlen  30
#define NWG   256

typedef __hip_bfloat16 bf16;
typedef short s16x8 __attribute__((ext_vector_type(8)));
typedef short s16x4 __attribute__((ext_vector_type(4)));
typedef float f32x4 __attribute__((ext_vector_type(4)));
typedef int   i32x2 __attribute__((ext_vector_type(2)));

__device__ __forceinline__ float bf2f(bf16 x){ return __bfloat162float(x); }
__device__ __forceinline__ bf16  f2bf(float x){ return __float2bfloat16(x); }
__device__ __forceinline__ float bfbits2f(short u){
    union { unsigned int ui; float f; } v;
    v.ui = ((unsigned int)(unsigned short)u) << 16;
    return v.f;
}
__device__ __forceinline__ short f2bfbits(float x){
    bf16 h = f2bf(x); short s; __builtin_memcpy(&s, &h, 2); return s;
}
__device__ __forceinline__ float sigm(float x){ return 1.0f/(1.0f + __expf(-x)); }
__device__ __forceinline__ float ftanh(float x){
    const float e = __expf(2.0f*x);
    return 1.0f - 2.0f/(e + 1.0f);
}
__device__ __forceinline__ i32x2 pack4(float a, float b, float c, float d){
    i32x2 v;
    v[0] = (int)(unsigned short)f2bfbits(a) | ((int)(unsigned short)f2bfbits(b) << 16);
    v[1] = (int)(unsigned short)f2bfbits(c) | ((int)(unsigned short)f2bfbits(d) << 16);
    return v;
}
// L3-bypass 8B load (sc0 sc1): reads the device coherence point.
__device__ __forceinline__ s16x4 sc_load_b64(const void* p){
    i32x2 v;
    asm volatile("global_load_dwordx2 %0, %1, off sc0 sc1\n\ts_waitcnt vmcnt(0)"
                 : "=v"(v) : "v"(p) : "memory");
    s16x4 r; __builtin_memcpy(&r, &v, 8); return r;
}

// ---------------- ws layout (bytes) ----------------
#define OFF_ABUF0   (0u)
#define OFF_ABUF1   (2u<<20)
#define OFF_ATTNAP  (8u<<20)
#define OFF_XDEC    (9u<<20)
#define OFF_FLAG    ((9u<<20) + (16u<<10))
#define OFF_COMBWR  ((9u<<20) + (32u<<10))
#define OFF_ATTNWR  ((9u<<20) + (600u<<10))
#define OFF_FLAGS   ((9u<<20) + (704u<<10))
#define OFF_WCACHE  (10u<<20)
#define OFF_ENCOUT  (18u<<20)

// wcache element offsets (bf16 elements), 8-elem aligned per array
#define WC_INPUT 0
#define WC_EWIH  204800
#define WC_EWHH  212992
#define WC_EBIH  1261568
#define WC_EBHH  1263616
#define WC_AW    1265664
#define WC_AB    1291464
#define WC_CW    1291520
#define WC_CB    1555712
#define WC_DWIH  1556224
#define WC_DWHH  2604800
#define WC_DBIH  3653376
#define WC_DBHH  3655424
#define WC_OW    3657472
#define WC_OB    3659520
#define WC_TOTAL 3659524

__device__ __constant__ int WOFF[15] = {
    WC_INPUT, WC_EWIH, WC_EWHH, WC_EBIH, WC_EBHH, WC_AW, WC_AB, WC_CW,
    WC_CB, WC_DWIH, WC_DWHH, WC_DBIH, WC_DBHH, WC_OW, WC_OB };
__device__ __constant__ int WNUM[15] = {
    204800, 8192, 1048576, 2048, 2048, 25800, 50, 264192,
    512, 1048576, 1048576, 2048, 2048, 2048, 4 };

struct Ptrs15 { const void* p[15]; };

__global__ void probe_kernel(const unsigned int* __restrict__ w, int* flag){
    __shared__ int cnt;
    if (threadIdx.x == 0) cnt = 0;
    __syncthreads();
    int c = 0;
    for (int i = threadIdx.x; i < 4096; i += 256){
        unsigned e = (w[i] >> 7) & 0xFFu;
        c += (e >= 0x80u) ? 1 : 0;
    }
    atomicAdd(&cnt, c);
    __syncthreads();
    if (threadIdx.x == 0) *flag = (cnt > 400) ? 1 : 0;
}

__global__ __launch_bounds__(256) void convert_kernel(
    Ptrs15 srcs, const int* __restrict__ flag, bf16* __restrict__ dst)
{
    const int f = *flag;
    for (int idx = blockIdx.x*256 + threadIdx.x; idx < WC_TOTAL;
         idx += gridDim.x*256){
        int a = 0;
#pragma unroll
        for (int j = 1; j < 15; ++j) if (idx >= WOFF[j]) a = j;
        const int local = idx - WOFF[a];
        if (local >= WNUM[a]) continue;
        bf16 v;
        if (f) v = f2bf(((const float*)srcs.p[a])[local]);
        else   v = ((const bf16*)srcs.p[a])[local];
        dst[idx] = v;
    }
}

__global__ __launch_bounds__(256) void setup_kernel(
    bf16* __restrict__ Abuf0, bf16* __restrict__ Abuf1,
    bf16* __restrict__ combWr, bf16* __restrict__ attnWr,
    const bf16* __restrict__ cWc, const bf16* __restrict__ aWc)
{
    const unsigned idx = blockIdx.x*256u + threadIdx.x;
    if (idx < (unsigned)Bsz*Hd){
        const unsigned row = idx >> 9, col = idx & (Hd-1);
        const bf16 z = f2bf(0.0f);
        Abuf0[(size_t)row*1024 + Hd + col] = z;
        Abuf1[(size_t)row*1024 + Hd + col] = z;
    }
    if (idx < (unsigned)Hd*Hd)
        combWr[idx] = cWc[(size_t)(idx >> 9)*(Hd+Din) + Din + (idx & (Hd-1))];
    if (idx < (unsigned)Lseq*Hd)
        attnWr[idx] = aWc[(size_t)(idx >> 9)*(Hd+Din) + Din + (idx & (Hd-1))];
}

struct MegaP {
    const bf16 *input, *eWih, *eWhh, *ebih, *ebhh;
    const bf16 *aW, *ab, *cW, *cb, *dWih, *dWhh, *dbih, *dbhh, *oW, *ob;
    const bf16 *combWr, *attnWr;
    bf16 *A0, *A1, *encout, *attnap, *xdec;
    int *wflag, *gflag, *xccmap;
    const int *flag;
    void *dout;
};

#define WSTRIDE 536   // LDS weight row stride in shorts (16B aligned, low-conflict)

// ---------------------------------------------------------------------------
// Persistent megakernel v3. 256 WGs x 512 thr, 1 WG/CU (~159.7 KB LDS).
// Tiling: grp = wg&7 owns batch rows grp*128..+128; rank = wg>>3 is the
// n-tile (64 gate-cols = 16 hcols). Verified vs HW_REG_XCC_ID; fallback to
// fully-fenced sync if the round-robin mapping doesn't hold.
//   - enc W_hh / dec W_ih / dec W_hh all LDS-resident (64-col slices).
//   - enc_out slice for the WG's 4 attn rows gathered ONCE into 100 VGPRs
//     (s16x8 ereg[25] per wave) -> dec context reads ZERO memory.
//   - h_r gather (only cross-XCD dependency) uses sc0/sc1 L3-bypass loads;
//     post-D3 sync = flag round + fence (wbl2) + L1-only inv. L2 NEVER wiped.
// ---------------------------------------------------------------------------
__global__ __launch_bounds__(512, 2) void mega_kernel(MegaP P)
{
    __shared__ short w1_lds[64*WSTRIDE];   // 68,608 B (dec W_ih slice)
    __shared__ short w2_lds[64*WSTRIDE];   // 68,608 B (enc W_hh, then dec W_hh)
    __shared__ short hr_s[4][Hd];          // 4 KB
    __shared__ float ctx_s[2][4][8][64];   // 16 KB
    __shared__ float aw_s[4][64];          // 1 KB
    __shared__ int   xmap_s[NWG];          // 1 KB
    __shared__ int   info_s[2];

    const int wg = blockIdx.x, tid = threadIdx.x;
    const int wave = tid >> 6, lane = tid & 63;
    const int quad = lane >> 4, l15 = lane & 15;
    const int lbase = lane & ~3;
    const int f32out = *P.flag;

    const int grp = wg & 7, rank = wg >> 3;

    int ep = 0;

    auto flag_round = [&](bool fence){
        ++ep;
        __syncthreads();
        if (tid == 0){
            if (fence) __threadfence();
            __hip_atomic_store(P.wflag + wg*16, ep, __ATOMIC_RELAXED, __HIP_MEMORY_SCOPE_SYSTEM);
        }
        if (rank == 0){
            if (tid < 32){
                int* f = P.wflag + (tid*8 + grp)*16;
                while (__hip_atomic_load(f, __ATOMIC_RELAXED, __HIP_MEMORY_SCOPE_SYSTEM) < ep)
                    __builtin_amdgcn_s_sleep(1);
            }
            __syncthreads();
            if (tid == 0)
                __hip_atomic_store(P.gflag + grp*16, ep, __ATOMIC_RELAXED, __HIP_MEMORY_SCOPE_SYSTEM);
        }
        if (tid < 8){
            int* f = P.gflag + tid*16;
            while (__hip_atomic_load(f, __ATOMIC_RELAXED, __HIP_MEMORY_SCOPE_SYSTEM) < ep)
                __builtin_amdgcn_s_sleep(1);
        }
        __syncthreads();
    };

    // full fallback: global + L2 invalidate (safe under any WG placement)
    auto GSYNCF = [&](){
        flag_round(true);
        asm volatile("buffer_inv sc0 sc1" ::: "memory");
        __syncthreads();
    };

    // ---- XCD mapping verification ----
    if (tid == 0){
        int xcc = 0;
        asm volatile("s_getreg_b32 %0, hwreg(HW_REG_XCC_ID)" : "=s"(xcc));
        P.xccmap[wg] = xcc & 7;
    }
    GSYNCF();
    if (tid < NWG) xmap_s[tid] = P.xccmap[tid];
    __syncthreads();
    if (tid == 0){
        int ok = 1;
        for (int g = 0; g < 8; ++g){
            const int x0 = xmap_s[g];
            for (int i = 1; i < 32; ++i) ok &= (xmap_s[i*8 + g] == x0);
        }
        info_s[0] = ok;
    }
    __syncthreads();
    const int bal = info_s[0];

    // global sync, L1-only inv (h goes to L3 via fence; L2 stays warm)
    auto GSYNCL = [&](){
        if (!bal){ GSYNCF(); return; }
        flag_round(true);
        asm volatile("buffer_inv" ::: "memory");
        __syncthreads();
    };
    // XCD-local sync, L1-only inv
    auto XSYNC = [&](){
        if (!bal){ GSYNCF(); return; }
        ++ep;
        __syncthreads();
        if (tid == 0)
            __hip_atomic_store(P.wflag + wg*16, ep, __ATOMIC_RELAXED, __HIP_MEMORY_SCOPE_SYSTEM);
        if (tid < 32){
            int* f = P.wflag + (tid*8 + grp)*16;
            while (__hip_atomic_load(f, __ATOMIC_RELAXED, __HIP_MEMORY_SCOPE_SYSTEM) < ep)
                __builtin_amdgcn_s_sleep(1);
        }
        __syncthreads();
        asm volatile("buffer_inv" ::: "memory");
    };

    bf16* bufs[2] = { P.A0, P.A1 };

    // ---- gates tiling: 128 rows x 64 gate-cols per WG ----
    const int bm0 = grp*128, hc0 = rank*16;
    const int wm = wave >> 1, wn = wave & 1;      // 4 x 2 waves (32x32 each)
    const int arow0 = bm0 + wm*32 + l15;

    int ng[2];
#pragma unroll
    for (int nf = 0; nf < 2; ++nf){
        const int n = wn*32 + nf*16 + l15;        // 0..63
        ng[nf] = (n & 3)*Hd + hc0 + (n >> 2);
    }

    // ================= ENCODER =================
    float bias_e[2], wxv_e[2][4];
#pragma unroll
    for (int nf = 0; nf < 2; ++nf){
        bias_e[nf] = bf2f(P.ebih[ng[nf]]) + bf2f(P.ebhh[ng[nf]]);
        const s16x4 t4 = *reinterpret_cast<const s16x4*>(P.eWih + (size_t)ng[nf]*Din);
#pragma unroll
        for (int d = 0; d < 4; ++d) wxv_e[nf][d] = bfbits2f(t4[d]);
    }

    // enc W_hh slice -> w2_lds  (64 local cols x 512 K)
    for (int i = tid; i < 64*64; i += 512){
        const int col = i >> 6, k8 = (i & 63)*8;
        const int g = (col & 3)*Hd + hc0 + (col >> 2);
        const s16x8 v = *reinterpret_cast<const s16x8*>(P.eWhh + (size_t)g*Hd + k8);
        *reinterpret_cast<s16x8*>(&w2_lds[col*WSTRIDE + k8]) = v;
    }
    __syncthreads();

    float creg[2][2][4];
#pragma unroll
    for (int a = 0; a < 2; ++a)
#pragma unroll
        for (int b = 0; b < 2; ++b)
#pragma unroll
            for (int r = 0; r < 4; ++r) creg[a][b][r] = 0.0f;

    for (int t = 0; t < Lseq; ++t){
        const bf16* Ain = bufs[t&1] + Hd;
        bf16* hout = bufs[(t+1)&1] + Hd;

        f32x4 acc[2][2];
#pragma unroll
        for (int mf=0; mf<2; ++mf)
#pragma unroll
            for (int nf=0; nf<2; ++nf) acc[mf][nf] = (f32x4)0.0f;

        s16x8 afr[2], bfr[2];
#pragma unroll
        for (int sl = 0; sl < 16; ++sl){
#pragma unroll
            for (int mf = 0; mf < 2; ++mf)
                afr[mf] = *reinterpret_cast<const s16x8*>(
                    Ain + (size_t)(arow0 + mf*16)*1024 + sl*32 + quad*8);
#pragma unroll
            for (int nf = 0; nf < 2; ++nf){
                const int nl = wn*32 + nf*16 + l15;
                bfr[nf] = *reinterpret_cast<const s16x8*>(
                    &w2_lds[nl*WSTRIDE + sl*32 + quad*8]);
            }
#pragma unroll
            for (int mf = 0; mf < 2; ++mf)
#pragma unroll
                for (int nf = 0; nf < 2; ++nf)
                    acc[mf][nf] = __builtin_amdgcn_mfma_f32_16x16x32_bf16(
                        afr[mf], bfr[nf], acc[mf][nf], 0, 0, 0);
        }

#pragma unroll
        for (int mf = 0; mf < 2; ++mf){
#pragma unroll
            for (int r = 0; r < 4; ++r){
                const int m = bm0 + wm*32 + mf*16 + quad*4 + r;
                const s16x4 xt = *reinterpret_cast<const s16x4*>(
                    P.input + ((size_t)m*Lseq + t)*Din);
                float xv[4];
#pragma unroll
                for (int d = 0; d < 4; ++d) xv[d] = bfbits2f(xt[d]);
#pragma unroll
                for (int nf = 0; nf < 2; ++nf){
                    const int n_loc = wn*32 + nf*16 + l15;
                    float gv = acc[mf][nf][r] + bias_e[nf]
                             + xv[0]*wxv_e[nf][0] + xv[1]*wxv_e[nf][1]
                             + xv[2]*wxv_e[nf][2] + xv[3]*wxv_e[nf][3];
                    const float gi = __shfl(gv, lbase+0);
                    const float gf = __shfl(gv, lbase+1);
                    const float gg = __shfl(gv, lbase+2);
                    const float go = __shfl(gv, lbase+3);
                    if ((lane & 3) == 0){
                        const int hcol = hc0 + (n_loc >> 2);
                        const float cn = sigm(gf)*creg[mf][nf][r] + sigm(gi)*ftanh(gg);
                        creg[mf][nf][r] = cn;
                        const float hv = sigm(go)*ftanh(cn);
                        const bf16 hb = f2bf(hv);
                        hout[(size_t)m*1024 + hcol] = hb;
                        P.encout[((size_t)m*Lseq + t)*Hd + hcol] = hb;
                    }
                }
            }
        }
        if (t == Lseq-1) GSYNCL(); else XSYNC();
    }

    // ================= DECODER setup =================
    // dec weights -> LDS
    for (int i = tid; i < 64*64; i += 512){
        const int col = i >> 6, k8 = (i & 63)*8;
        const int g = (col & 3)*Hd + hc0 + (col >> 2);
        *reinterpret_cast<s16x8*>(&w1_lds[col*WSTRIDE + k8]) =
            *reinterpret_cast<const s16x8*>(P.dWih + (size_t)g*Hd + k8);
        *reinterpret_cast<s16x8*>(&w2_lds[col*WSTRIDE + k8]) =
            *reinterpret_cast<const s16x8*>(P.dWhh + (size_t)g*Hd + k8);
    }

    float bias_d[2];
#pragma unroll
    for (int nf = 0; nf < 2; ++nf)
        bias_d[nf] = bf2f(P.dbih[ng[nf]]) + bf2f(P.dbhh[ng[nf]]);

    const int b0 = grp*128 + rank*4;
    const int s_uni = b0 >> 9;
    const int p0 = b0 & (Hd-1);

    // enc_out slice -> registers: wave (rr, half) holds row b0+rr, l = half*25+i
    const int rr = wave & 3, half = wave >> 2;
    s16x8 ereg[25];
    {
        const bf16* eb = P.encout + (size_t)(b0 + rr)*Lseq*Hd + lane*8;
#pragma unroll
        for (int i = 0; i < 25; ++i)
            ereg[i] = *reinterpret_cast<const s16x8*>(eb + (size_t)(half*25 + i)*Hd);
    }

    // comb tile: wave covers rows bm0+wave*16, cols ccol
    const int ccol = hc0 + l15;   // 16 comb cols per WG (rank*16..+16)
    float bias_c, wxv_c[4];
    {
        bias_c = bf2f(P.cb[ccol]);
        const s16x4 t4 = *reinterpret_cast<const s16x4*>(P.cW + (size_t)ccol*(Hd+Din));
#pragma unroll
        for (int d = 0; d < 4; ++d) wxv_c[d] = bfbits2f(t4[d]);
    }
    __syncthreads();  // LDS fills complete

    for (int t = 0; t < Tlen; ++t){
        const int p = t & 1;
        const bf16* hprev = bufs[p] + Hd;

        // ---- D1: hr staging (L3-bypass) + pred(t-1) + attention ----
        {
            const s16x4 hv = sc_load_b64(hprev + (size_t)(2*tid + s_uni)*1024 + p0);
            hr_s[0][tid] = hv[0]; hr_s[1][tid] = hv[1];
            hr_s[2][tid] = hv[2]; hr_s[3][tid] = hv[3];
        }
        __syncthreads();

        if (wave < 4){
            const int b = b0 + wave;
            float x0, x1, x2, x3;
            if (t == 0){
                const bf16* xp = P.input + ((size_t)b*Lseq + (Lseq-1))*Din;
                x0 = bf2f(xp[0]); x1 = bf2f(xp[1]); x2 = bf2f(xp[2]); x3 = bf2f(xp[3]);
            } else {
                float q0=0.f, q1=0.f, q2=0.f, q3=0.f;
                const bf16* hb = hprev + (size_t)b*1024;
                for (int k = lane; k < Hd; k += 64){
                    const float hv = bf2f(hb[k]);
                    q0 += hv*bf2f(P.oW[k]);
                    q1 += hv*bf2f(P.oW[Hd+k]);
                    q2 += hv*bf2f(P.oW[2*Hd+k]);
                    q3 += hv*bf2f(P.oW[3*Hd+k]);
                }
#pragma unroll
                for (int off = 32; off; off >>= 1){
                    q0 += __shfl_down(q0, off); q1 += __shfl_down(q1, off);
                    q2 += __shfl_down(q2, off); q3 += __shfl_down(q3, off);
                }
                x0 = __shfl(q0,0) + bf2f(P.ob[0]);
                x1 = __shfl(q1,0) + bf2f(P.ob[1]);
                x2 = __shfl(q2,0) + bf2f(P.ob[2]);
                x3 = __shfl(q3,0) + bf2f(P.ob[3]);
                if (lane == 0){
                    const size_t o = ((size_t)b*Tlen + (t-1))*Din;
                    if (f32out){
                        float* dp = (float*)P.dout + o;
                        dp[0]=x0; dp[1]=x1; dp[2]=x2; dp[3]=x3;
                    } else {
                        *reinterpret_cast<i32x2*>((bf16*)P.dout + o) = pack4(x0,x1,x2,x3);
                    }
                }
            }
            if (lane == 0)
                *reinterpret_cast<i32x2*>(P.xdec + (size_t)b*Din) = pack4(x0,x1,x2,x3);

            float logit = -3.0e38f;
            if (lane < Lseq){
                float a0 = bf2f(P.ab[lane]);
                {
                    const bf16* wx = P.aW + (size_t)lane*(Hd+Din);
                    a0 += x0*bf2f(wx[0]) + x1*bf2f(wx[1]) + x2*bf2f(wx[2]) + x3*bf2f(wx[3]);
                }
                float a1 = 0.f, a2 = 0.f, a3 = 0.f;
                const bf16* wr = P.attnWr + (size_t)lane*Hd;
                for (int j = 0; j < Hd; j += 16){
                    float t4[4] = {0.f,0.f,0.f,0.f};
#pragma unroll
                    for (int q = 0; q < 4; ++q){
                        const s16x4 hw = *reinterpret_cast<const s16x4*>(&hr_s[wave][j + q*4]);
                        const s16x4 wv = *reinterpret_cast<const s16x4*>(wr + j + q*4);
                        t4[q] = bfbits2f(hw[0])*bfbits2f(wv[0]) + bfbits2f(hw[1])*bfbits2f(wv[1])
                              + bfbits2f(hw[2])*bfbits2f(wv[2]) + bfbits2f(hw[3])*bfbits2f(wv[3]);
                    }
                    a0 += t4[0]; a1 += t4[1]; a2 += t4[2]; a3 += t4[3];
                }
                logit = (a0 + a1) + (a2 + a3);
            }
            float mx = logit;
#pragma unroll
            for (int off = 32; off; off >>= 1) mx = fmaxf(mx, __shfl_xor(mx, off));
            const float e = (lane < Lseq) ? __expf(logit - mx) : 0.0f;
            float se = e;
#pragma unroll
            for (int off = 32; off; off >>= 1) se += __shfl_xor(se, off);
            aw_s[wave][lane] = e / se;
        }
        __syncthreads();

        // context entirely from registers
        {
            float acc8[8] = {0.f,0.f,0.f,0.f,0.f,0.f,0.f,0.f};
#pragma unroll
            for (int i = 0; i < 25; ++i){
                const float w = aw_s[rr][half*25 + i];
#pragma unroll
                for (int q = 0; q < 8; ++q) acc8[q] += w * bfbits2f(ereg[i][q]);
            }
#pragma unroll
            for (int q = 0; q < 8; ++q) ctx_s[half][rr][q][lane] = acc8[q];
        }
        __syncthreads();

        if (wave < 4){
            const int b = b0 + wave;
            s16x8 ov;
#pragma unroll
            for (int q = 0; q < 8; ++q)
                ov[q] = f2bfbits(ctx_s[0][wave][q][lane] + ctx_s[1][wave][q][lane]);
            *reinterpret_cast<s16x8*>(P.attnap + (size_t)b*Hd + lane*8) = ov;
        }
        XSYNC();

        // ---- D2: comb GEMM (128 rows x 16 cols per WG) ----
        {
            f32x4 cacc = (f32x4)0.0f;
            const bf16* Ab = P.attnap + (size_t)(bm0 + wave*16 + l15)*Hd + quad*8;
#pragma unroll
            for (int kk = 0; kk < 16; ++kk){
                const s16x8 bfr = *reinterpret_cast<const s16x8*>(
                    P.combWr + (size_t)ccol*Hd + kk*32 + quad*8);
                const s16x8 afr2 = *reinterpret_cast<const s16x8*>(Ab + kk*32);
                cacc = __builtin_amdgcn_mfma_f32_16x16x32_bf16(afr2, bfr, cacc, 0, 0, 0);
            }
            bf16* outp = bufs[p];
#pragma unroll
            for (int r = 0; r < 4; ++r){
                const int m = bm0 + wave*16 + quad*4 + r;
                const s16x4 xt = *reinterpret_cast<const s16x4*>(P.xdec + (size_t)m*Din);
                float v = cacc[r] + bias_c
                        + bfbits2f(xt[0])*wxv_c[0] + bfbits2f(xt[1])*wxv_c[1]
                        + bfbits2f(xt[2])*wxv_c[2] + bfbits2f(xt[3])*wxv_c[3];
                v = fmaxf(v, 0.0f);
                outp[(size_t)m*1024 + ccol] = f2bf(v);
            }
        }
        XSYNC();

        // ---- D3: dec gates (K=1024: w1=W_ih, w2=W_hh from LDS) ----
        {
            const bf16* Ain = bufs[p];
            bf16* hout = bufs[p^1] + Hd;
            f32x4 acc[2][2];
#pragma unroll
            for (int mf=0; mf<2; ++mf)
#pragma unroll
                for (int nf=0; nf<2; ++nf) acc[mf][nf] = (f32x4)0.0f;

            s16x8 afr[2], bfr[2];
#pragma unroll
            for (int sl = 0; sl < 16; ++sl){
#pragma unroll
                for (int mf = 0; mf < 2; ++mf)
                    afr[mf] = *reinterpret_cast<const s16x8*>(
                        Ain + (size_t)(arow0 + mf*16)*1024 + sl*32 + quad*8);
#pragma unroll
                for (int nf = 0; nf < 2; ++nf){
                    const int nl = wn*32 + nf*16 + l15;
                    bfr[nf] = *reinterpret_cast<const s16x8*>(
                        &w1_lds[nl*WSTRIDE + sl*32 + quad*8]);
                }
#pragma unroll
                for (int mf = 0; mf < 2; ++mf)
#pragma unroll
                    for (int nf = 0; nf < 2; ++nf)
                        acc[mf][nf] = __builtin_amdgcn_mfma_f32_16x16x32_bf16(
                            afr[mf], bfr[nf], acc[mf][nf], 0, 0, 0);
            }
#pragma unroll
            for (int sl = 0; sl < 16; ++sl){
#pragma unroll
                for (int mf = 0; mf < 2; ++mf)
                    afr[mf] = *reinterpret_cast<const s16x8*>(
                        Ain + (size_t)(arow0 + mf*16)*1024 + Hd + sl*32 + quad*8);
#pragma unroll
                for (int nf = 0; nf < 2; ++nf){
                    const int nl = wn*32 + nf*16 + l15;
                    bfr[nf] = *reinterpret_cast<const s16x8*>(
                        &w2_lds[nl*WSTRIDE + sl*32 + quad*8]);
                }
#pragma unroll
                for (int mf = 0; mf < 2; ++mf)
#pragma unroll
                    for (int nf = 0; nf < 2; ++nf)
                        acc[mf][nf] = __builtin_amdgcn_mfma_f32_16x16x32_bf16(
                            afr[mf], bfr[nf], acc[mf][nf], 0, 0, 0);
            }

#pragma unroll
            for (int mf = 0; mf < 2; ++mf){
#pragma unroll
                for (int r = 0; r < 4; ++r){
                    const int m = bm0 + wm*32 + mf*16 + quad*4 + r;
#pragma unroll
                    for (int nf = 0; nf < 2; ++nf){
                        const int n_loc = wn*32 + nf*16 + l15;
                        float gv = acc[mf][nf][r] + bias_d[nf];
                        const float gi = __shfl(gv, lbase+0);
                        const float gf = __shfl(gv, lbase+1);
                        const float gg = __shfl(gv, lbase+2);
                        const float go = __shfl(gv, lbase+3);
                        if ((lane & 3) == 0){
                            const int hcol = hc0 + (n_loc >> 2);
                            const float cn = sigm(gf)*creg[mf][nf][r] + sigm(gi)*ftanh(gg);
                            creg[mf][nf][r] = cn;
                            const float hv = sigm(go)*ftanh(cn);
                            hout[(size_t)m*1024 + hcol] = f2bf(hv);
                        }
                    }
                }
            }
        }
        GSYNCL();   // flush h to L3 (fence) + L1 inv; L2 stays warm
    }

    // ---- final pred (t = T-1) ----
    if (wave < 4){
        const int b = b0 + wave;
        const bf16* hb = bufs[Tlen & 1] + Hd + (size_t)b*1024;
        float q0=0.f, q1=0.f, q2=0.f, q3=0.f;
        for (int k = lane; k < Hd; k += 64){
            const float hv = bf2f(hb[k]);
            q0 += hv*bf2f(P.oW[k]);
            q1 += hv*bf2f(P.oW[Hd+k]);
            q2 += hv*bf2f(P.oW[2*Hd+k]);
            q3 += hv*bf2f(P.oW[3*Hd+k]);
        }
#pragma unroll
        for (int off = 32; off; off >>= 1){
            q0 += __shfl_down(q0, off); q1 += __shfl_down(q1, off);
            q2 += __shfl_down(q2, off); q3 += __shfl_down(q3, off);
        }
        if (lane == 0){
            const size_t o = ((size_t)b*Tlen + (Tlen-1))*Din;
            const float r0 = q0 + bf2f(P.ob[0]), r1 = q1 + bf2f(P.ob[1]);
            const float r2 = q2 + bf2f(P.ob[2]), r3 = q3 + bf2f(P.ob[3]);
            if (f32out){
                float* dp = (float*)P.dout + o;
                dp[0]=r0; dp[1]=r1; dp[2]=r2; dp[3]=r3;
            } else {
                *reinterpret_cast<i32x2*>((bf16*)P.dout + o) = pack4(r0,r1,r2,r3);
            }
        }
    }
}

extern "C" void kernel_launch(void* const* d_in, const int* in_sizes, int n_in,
                              void* d_out, int out_size, void* d_ws, size_t ws_size,
                              hipStream_t stream)
{
    char* ws = (char*)d_ws;
    bf16*  Abuf0   = (bf16*)(ws + OFF_ABUF0);
    bf16*  Abuf1   = (bf16*)(ws + OFF_ABUF1);
    bf16*  attnap  = (bf16*)(ws + OFF_ATTNAP);
    bf16*  xdec    = (bf16*)(ws + OFF_XDEC);
    int*   flag    = (int*)(ws + OFF_FLAG);
    bf16*  combWr  = (bf16*)(ws + OFF_COMBWR);
    bf16*  attnWr  = (bf16*)(ws + OFF_ATTNWR);
    int*   flags   = (int*)(ws + OFF_FLAGS);
    bf16*  wc      = (bf16*)(ws + OFF_WCACHE);
    bf16*  enc_out = (bf16*)(ws + OFF_ENCOUT);

    hipMemsetAsync(flags, 0, 20480, stream);

    probe_kernel<<<1, 256, 0, stream>>>((const unsigned int*)d_in[3], flag);

    Ptrs15 srcs;
    srcs.p[0]=d_in[0];  srcs.p[1]=d_in[2];  srcs.p[2]=d_in[3];  srcs.p[3]=d_in[4];
    srcs.p[4]=d_in[5];  srcs.p[5]=d_in[6];  srcs.p[6]=d_in[7];  srcs.p[7]=d_in[8];
    srcs.p[8]=d_in[9];  srcs.p[9]=d_in[10]; srcs.p[10]=d_in[11];srcs.p[11]=d_in[12];
    srcs.p[12]=d_in[13];srcs.p[13]=d_in[14];srcs.p[14]=d_in[15];
    convert_kernel<<<1024, 256, 0, stream>>>(srcs, flag, wc);

    setup_kernel<<<2048, 256, 0, stream>>>(Abuf0, Abuf1, combWr, attnWr,
                                           wc+WC_CW, wc+WC_AW);

    MegaP P;
    P.input = wc+WC_INPUT; P.eWih = wc+WC_EWIH; P.eWhh = wc+WC_EWHH;
    P.ebih = wc+WC_EBIH;   P.ebhh = wc+WC_EBHH;
    P.aW = wc+WC_AW;  P.ab = wc+WC_AB;  P.cW = wc+WC_CW;  P.cb = wc+WC_CB;
    P.dWih = wc+WC_DWIH; P.dWhh = wc+WC_DWHH; P.dbih = wc+WC_DBIH; P.dbhh = wc+WC_DBHH;
    P.oW = wc+WC_OW;  P.ob = wc+WC_OB;
    P.combWr = combWr; P.attnWr = attnWr;
    P.A0 = Abuf0; P.A1 = Abuf1; P.encout = enc_out; P.attnap = attnap; P.xdec = xdec;
    P.wflag = flags; P.gflag = flags + 256*16; P.xccmap = flags + 256*16 + 8*16;
    P.flag = flag; P.dout = d_out;

    mega_kernel<<<NWG, 512, 0, stream>>>(P);
}